// Round 5
// baseline (144.109 us; speedup 1.0000x reference)
//
#include <hip/hip_runtime.h>
#include <cstdint>

#define NV 200000
#define NCOLS 5
#define P 128
#define NE 8192
#define NC 1024
#define KPAD 40                 // shorts per point row (80 B): 16 fp16 slots + pad, 16B-aligned rows

typedef _Float16 half8 __attribute__((ext_vector_type(8)));
typedef float   float4v __attribute__((ext_vector_type(4)));

// ---------------- Kernel 1: per-cluster gather + fp16-split fragment build ----------------
// Per point: dense float4 coords; A-form row (16 fp16 K-slots); B-form row.
// K-slot pairing (C = sum_k A[i,k]*B[k,j] = |a|^2 + |b|^2 - 2 a.b, up to fp16-split error):
//   k0-2 : A = a_hi        B = -2*b_hi
//   k3-5 : A = a_lo        B = -2*b_hi
//   k6-8 : A = a_hi        B = -2*b_lo
//   k9   : A = |a|^2_hi    B = 1
//   k10  : A = |a|^2_lo    B = 1
//   k11  : A = 1           B = |b|^2_hi
//   k12  : A = 1           B = |b|^2_lo
//   k13+ : 0
__global__ __launch_bounds__(256) void gather_kernel(
    const float* __restrict__ data,
    const int*   __restrict__ clusts,
    float4*      __restrict__ dense,
    short*       __restrict__ wsA,
    short*       __restrict__ wsB,
    int*         __restrict__ b2max)
{
    const int idx = blockIdx.x * 256 + threadIdx.x;   // 0 .. NC*P-1
    const int v = clusts[idx];
    const float x = data[v * NCOLS + 1];
    const float y = data[v * NCOLS + 2];
    const float z = data[v * NCOLS + 3];
    dense[idx] = make_float4(x, y, z, 0.f);

    const _Float16 xh = (_Float16)x, yh = (_Float16)y, zh = (_Float16)z;
    const float xhf = (float)xh, yhf = (float)yh, zhf = (float)zh;
    const _Float16 xl = (_Float16)(x - xhf);   // Sterbenz: x - xhf exact in fp32
    const _Float16 yl = (_Float16)(y - yhf);
    const _Float16 zl = (_Float16)(z - zhf);

    const float a2 = x * x + y * y + z * z;
    const _Float16 a2h = (_Float16)a2;
    const _Float16 a2l = (_Float16)(a2 - (float)a2h);
    const _Float16 one = (_Float16)1.0f;
    const _Float16 n2  = (_Float16)(-2.0f);
    const _Float16 m2xh = n2 * xh, m2yh = n2 * yh, m2zh = n2 * zh;  // exact (x2)
    const _Float16 m2xl = n2 * xl, m2yl = n2 * yl, m2zl = n2 * zl;

    _Float16 rowA[KPAD];
    _Float16 rowB[KPAD];
    #pragma unroll
    for (int k = 0; k < KPAD; ++k) { rowA[k] = (_Float16)0.f; rowB[k] = (_Float16)0.f; }
    rowA[0] = xh;  rowA[1] = yh;  rowA[2] = zh;
    rowA[3] = xl;  rowA[4] = yl;  rowA[5] = zl;
    rowA[6] = xh;  rowA[7] = yh;  rowA[8] = zh;
    rowA[9] = a2h; rowA[10] = a2l; rowA[11] = one; rowA[12] = one;

    rowB[0] = m2xh; rowB[1] = m2yh; rowB[2] = m2zh;
    rowB[3] = m2xh; rowB[4] = m2yh; rowB[5] = m2zh;
    rowB[6] = m2xl; rowB[7] = m2yl; rowB[8] = m2zl;
    rowB[9] = one;  rowB[10] = one; rowB[11] = a2h; rowB[12] = a2l;

    ulonglong2* dA = (ulonglong2*)(wsA + (size_t)idx * KPAD);   // 80B rows, 16B-aligned
    ulonglong2* dB = (ulonglong2*)(wsB + (size_t)idx * KPAD);
    const ulonglong2* sAp = (const ulonglong2*)rowA;
    const ulonglong2* sBp = (const ulonglong2*)rowB;
    #pragma unroll
    for (int k = 0; k < 5; ++k) { dA[k] = sAp[k]; dB[k] = sBp[k]; }

    // global max coord^2 (for rigorous filter margin); poison 0xAAAAAAAA is a
    // large negative int, so int atomicMax with positive-float bits works.
    float mm = fmaxf(fmaxf(x * x, y * y), z * z);
    for (int off = 32; off > 0; off >>= 1)
        mm = fmaxf(mm, __shfl_down(mm, off, 64));
    if ((threadIdx.x & 63) == 0) atomicMax(b2max, __float_as_int(mm));
}

// ---------------- Kernel 2: MFMA distance filter + exact rescoring ----------------
__global__ __launch_bounds__(256) void edge_kernel(
    const float4* __restrict__ dense,
    const short*  __restrict__ wsA,
    const short*  __restrict__ wsB,
    const int*    __restrict__ edge_index,
    const float*  __restrict__ b2max,
    float*        __restrict__ out)
{
    #pragma clang fp contract(off)   // exact path must match reference rounding

    const int e = blockIdx.x;
    const int t = threadIdx.x;

    __shared__ short sA[P * KPAD];           // 10240 B
    __shared__ short sB[P * KPAD];
    __shared__ float wfmin[4];
    __shared__ unsigned long long wmin[4];

    const int c1 = edge_index[e];
    const int c2 = edge_index[NE + e];

    // Coalesced 2x10KB stage of both clusters' fragment rows.
    {
        const ulonglong2* gA = (const ulonglong2*)(wsA + (size_t)c1 * P * KPAD);
        const ulonglong2* gB = (const ulonglong2*)(wsB + (size_t)c2 * P * KPAD);
        ulonglong2* lA = (ulonglong2*)sA;
        ulonglong2* lB = (ulonglong2*)sB;
        for (int i = t; i < 640; i += 256) { lA[i] = gA[i]; lB[i] = gB[i]; }
    }
    __syncthreads();

    const int lane = t & 63, w = t >> 6;
    const int m = lane & 15, quad = lane >> 4;

    // A frags: wave w owns rows [32w, 32w+32) as two 16-row tiles.
    const half8 a0 = *(const half8*)&sA[(w * 32 +      m) * KPAD + quad * 8];
    const half8 a1 = *(const half8*)&sA[(w * 32 + 16 + m) * KPAD + quad * 8];

    float4v acc[2][8];
    #pragma unroll
    for (int tr = 0; tr < 2; ++tr)
        #pragma unroll
        for (int tc = 0; tc < 8; ++tc)
            acc[tr][tc] = (float4v){0.f, 0.f, 0.f, 0.f};

    #pragma unroll
    for (int tc = 0; tc < 8; ++tc) {
        const half8 b = *(const half8*)&sB[(tc * 16 + m) * KPAD + quad * 8];
        acc[0][tc] = __builtin_amdgcn_mfma_f32_16x16x32_f16(a0, b, acc[0][tc], 0, 0, 0);
        acc[1][tc] = __builtin_amdgcn_mfma_f32_16x16x32_f16(a1, b, acc[1][tc], 0, 0, 0);
    }

    // Per-tile and per-lane min of the approximate distances.
    float tmin[16];
    #pragma unroll
    for (int tr = 0; tr < 2; ++tr)
        #pragma unroll
        for (int tc = 0; tc < 8; ++tc) {
            const float4v vv = acc[tr][tc];
            tmin[tr * 8 + tc] = fminf(fminf(vv.x, vv.y), fminf(vv.z, vv.w));
        }
    float mymin = tmin[0];
    #pragma unroll
    for (int k = 1; k < 16; ++k) mymin = fminf(mymin, tmin[k]);

    for (int off = 32; off > 0; off >>= 1)
        mymin = fminf(mymin, __shfl_down(mymin, off, 64));
    if (lane == 0) wfmin[w] = mymin;
    __syncthreads();
    const float smin = fminf(fminf(wfmin[0], wfmin[1]), fminf(wfmin[2], wfmin[3]));

    // Rigorous filter margin: fp16-split error <= ~1.5e-4*B2 + denorm-flush slack.
    const float B2 = *b2max;
    const float tau = smin + (1.5e-4f * B2 + 8.0e-3f);

    // Exact rescoring of candidates only (reference fp32 rounding + tie-break).
    unsigned long long bestkey = ~0ull;
    #pragma unroll
    for (int tr = 0; tr < 2; ++tr) {
        #pragma unroll
        for (int tc = 0; tc < 8; ++tc) {
            if (tmin[tr * 8 + tc] <= tau) {
                const float4v vv = acc[tr][tc];
                #pragma unroll
                for (int r = 0; r < 4; ++r) {
                    const float sv = (r == 0) ? vv.x : (r == 1) ? vv.y : (r == 2) ? vv.z : vv.w;
                    if (sv <= tau) {
                        // C/D layout: col = lane&15, row = quad*4 + r
                        const int i = w * 32 + tr * 16 + quad * 4 + r;
                        const int j = tc * 16 + m;
                        const float4 pa = dense[c1 * P + i];
                        const float4 pb = dense[c2 * P + j];
                        const float dx = __fsub_rn(pa.x, pb.x);
                        const float dy = __fsub_rn(pa.y, pb.y);
                        const float dz = __fsub_rn(pa.z, pb.z);
                        const float d2 = __fadd_rn(__fadd_rn(__fmul_rn(dx, dx), __fmul_rn(dy, dy)),
                                                   __fmul_rn(dz, dz));
                        const unsigned long long key =
                            ((unsigned long long)__float_as_uint(d2) << 32) |
                            (unsigned)(i * P + j);
                        if (key < bestkey) bestkey = key;
                    }
                }
            }
        }
    }

    for (int off = 32; off > 0; off >>= 1) {
        unsigned long long other = __shfl_down(bestkey, off, 64);
        if (other < bestkey) bestkey = other;
    }
    if (lane == 0) wmin[w] = bestkey;
    __syncthreads();

    if (t == 0) {
        unsigned long long k0 = wmin[0];
        #pragma unroll
        for (int q = 1; q < 4; ++q) if (wmin[q] < k0) k0 = wmin[q];
        const int flat = (int)(k0 & 0xffffffffull);
        const int i1 = flat >> 7;
        const int i2 = flat & (P - 1);

        const float4 p1 = dense[c1 * P + i1];
        const float4 p2 = dense[c2 * P + i2];
        const float v1x = p1.x, v1y = p1.y, v1z = p1.z;
        const float v2x = p2.x, v2y = p2.y, v2z = p2.z;

        const float dx = v1x - v2x, dy = v1y - v2y, dz = v1z - v2z;
        const float lend = sqrtf(dx * dx + dy * dy + dz * dz);

        float nx, ny, nz;
        if (lend > 0.f) { nx = dx / lend; ny = dy / lend; nz = dz / lend; }
        else            { nx = dx;        ny = dy;        nz = dz;        }

        const float B[9] = { nx*nx, nx*ny, nx*nz,
                             ny*nx, ny*ny, ny*nz,
                             nz*nx, nz*ny, nz*nz };

        float* o = out + (size_t)e * 38;
        o[0] = v1x; o[1] = v1y; o[2] = v1z;
        o[3] = v2x; o[4] = v2y; o[5] = v2z;
        o[6] = nx;  o[7] = ny;  o[8] = nz;  o[9] = lend;
        #pragma unroll
        for (int q = 0; q < 9; ++q) o[10 + q] = B[q];
        o[19] = v2x; o[20] = v2y; o[21] = v2z;
        o[22] = v1x; o[23] = v1y; o[24] = v1z;
        o[25] = -nx; o[26] = -ny; o[27] = -nz; o[28] = lend;
        #pragma unroll
        for (int q = 0; q < 9; ++q) o[29 + q] = B[q];
    }
}

// ---------------- Fallback (ws too small): round-2 exact kernel ----------------
__global__ __launch_bounds__(256) void exact_kernel(
    const float* __restrict__ data,
    const int*   __restrict__ clusts,
    const int*   __restrict__ edge_index,
    float*       __restrict__ out)
{
    #pragma clang fp contract(off)
    const int e = blockIdx.x;
    const int t = threadIdx.x;
    __shared__ float4 x1s[P];
    __shared__ float4 x2s[P];
    __shared__ unsigned long long wmin[4];
    const int c1 = edge_index[e];
    const int c2 = edge_index[NE + e];
    if (t < P) {
        const int v = clusts[c1 * P + t];
        x1s[t] = make_float4(data[v*NCOLS+1], data[v*NCOLS+2], data[v*NCOLS+3], 0.f);
    } else {
        const int p = t - P;
        const int v = clusts[c2 * P + p];
        x2s[p] = make_float4(data[v*NCOLS+1], data[v*NCOLS+2], data[v*NCOLS+3], 0.f);
    }
    __syncthreads();
    const int tj = t & 15, ti = t >> 4;
    float4 a[8], b[8];
    #pragma unroll
    for (int k = 0; k < 8; ++k) a[k] = x1s[ti + 16*k];
    #pragma unroll
    for (int mm = 0; mm < 8; ++mm) b[mm] = x2s[tj + 16*mm];
    float bd[8]; int bj[8];
    #pragma unroll
    for (int k = 0; k < 8; ++k) { bd[k] = __builtin_inff(); bj[k] = 0; }
    #pragma unroll
    for (int mm = 0; mm < 8; ++mm) {
        const int j = tj + 16*mm;
        #pragma unroll
        for (int k = 0; k < 8; ++k) {
            const float dx = __fsub_rn(a[k].x, b[mm].x);
            const float dy = __fsub_rn(a[k].y, b[mm].y);
            const float dz = __fsub_rn(a[k].z, b[mm].z);
            const float d2 = __fadd_rn(__fadd_rn(__fmul_rn(dx,dx), __fmul_rn(dy,dy)), __fmul_rn(dz,dz));
            if (d2 < bd[k]) { bd[k] = d2; bj[k] = j; }
        }
    }
    float bestd = __builtin_inff(); int bestflat = 0;
    #pragma unroll
    for (int k = 0; k < 8; ++k)
        if (bd[k] < bestd) { bestd = bd[k]; bestflat = (ti + 16*k) * P + bj[k]; }
    unsigned long long key = ((unsigned long long)__float_as_uint(bestd) << 32) | (unsigned)bestflat;
    for (int off = 32; off > 0; off >>= 1) {
        unsigned long long other = __shfl_down(key, off, 64);
        if (other < key) key = other;
    }
    if ((t & 63) == 0) wmin[t >> 6] = key;
    __syncthreads();
    if (t == 0) {
        unsigned long long k0 = wmin[0];
        #pragma unroll
        for (int q = 1; q < 4; ++q) if (wmin[q] < k0) k0 = wmin[q];
        const int flat = (int)(k0 & 0xffffffffull);
        const int i1 = flat >> 7, i2 = flat & (P - 1);
        const float v1x = x1s[i1].x, v1y = x1s[i1].y, v1z = x1s[i1].z;
        const float v2x = x2s[i2].x, v2y = x2s[i2].y, v2z = x2s[i2].z;
        const float dx = v1x - v2x, dy = v1y - v2y, dz = v1z - v2z;
        const float lend = sqrtf(dx*dx + dy*dy + dz*dz);
        float nx, ny, nz;
        if (lend > 0.f) { nx = dx/lend; ny = dy/lend; nz = dz/lend; }
        else            { nx = dx; ny = dy; nz = dz; }
        const float B[9] = { nx*nx, nx*ny, nx*nz, ny*nx, ny*ny, ny*nz, nz*nx, nz*ny, nz*nz };
        float* o = out + (size_t)e * 38;
        o[0]=v1x; o[1]=v1y; o[2]=v1z; o[3]=v2x; o[4]=v2y; o[5]=v2z;
        o[6]=nx; o[7]=ny; o[8]=nz; o[9]=lend;
        #pragma unroll
        for (int q = 0; q < 9; ++q) o[10+q] = B[q];
        o[19]=v2x; o[20]=v2y; o[21]=v2z; o[22]=v1x; o[23]=v1y; o[24]=v1z;
        o[25]=-nx; o[26]=-ny; o[27]=-nz; o[28]=lend;
        #pragma unroll
        for (int q = 0; q < 9; ++q) o[29+q] = B[q];
    }
}

extern "C" void kernel_launch(void* const* d_in, const int* in_sizes, int n_in,
                              void* d_out, int out_size, void* d_ws, size_t ws_size,
                              hipStream_t stream) {
    const float* data       = (const float*)d_in[0];
    const int*   clusts     = (const int*)d_in[1];
    const int*   edge_index = (const int*)d_in[2];
    float*       out        = (float*)d_out;

    char* wsc = (char*)d_ws;
    const size_t denseOff = 256;
    const size_t denseBytes = (size_t)NC * P * sizeof(float4);          // 2 MB
    const size_t fragBytes  = (size_t)NC * P * KPAD * sizeof(short);    // 10.5 MB
    const size_t need = denseOff + denseBytes + 2 * fragBytes;          // ~23.3 MB

    if (ws_size >= need) {
        int*    b2max = (int*)wsc;
        float4* dense = (float4*)(wsc + denseOff);
        short*  wsA   = (short*)(wsc + denseOff + denseBytes);
        short*  wsB   = wsA + (size_t)NC * P * KPAD;
        gather_kernel<<<(NC * P) / 256, 256, 0, stream>>>(data, clusts, dense, wsA, wsB, b2max);
        edge_kernel<<<NE, 256, 0, stream>>>(dense, wsA, wsB, edge_index,
                                            (const float*)b2max, out);
    } else {
        exact_kernel<<<NE, 256, 0, stream>>>(data, clusts, edge_index, out);
    }
}

// Round 6
// 129.064 us; speedup vs baseline: 1.1166x; 1.1166x over previous
//
#include <hip/hip_runtime.h>
#include <cstdint>

#define NV 200000
#define NCOLS 5
#define P 128
#define NE 8192
#define NC 1024
#define KROW 40   // shorts per LDS fragment row (80 B = 16B-aligned, 20-bank stride -> 2-way = free)

typedef _Float16 half8 __attribute__((ext_vector_type(8)));
typedef float   float4v __attribute__((ext_vector_type(4)));

// ---------------- Kernel 1: gather dense coords + global max coord^2 ----------------
__global__ __launch_bounds__(256) void gather_kernel(
    const float* __restrict__ data,
    const int*   __restrict__ clusts,
    float4*      __restrict__ dense,
    int*         __restrict__ b2max)
{
    const int idx = blockIdx.x * 256 + threadIdx.x;   // 0 .. NC*P-1
    const int v = clusts[idx];
    const float x = data[v * NCOLS + 1];
    const float y = data[v * NCOLS + 2];
    const float z = data[v * NCOLS + 3];
    dense[idx] = make_float4(x, y, z, 0.f);

    // global max coord^2 (rigorous filter margin); ws poison 0xAAAAAAAA is a
    // large negative int, so int atomicMax with positive-float bits works.
    float mm = fmaxf(fmaxf(x * x, y * y), z * z);
    for (int off = 32; off > 0; off >>= 1)
        mm = fmaxf(mm, __shfl_down(mm, off, 64));
    if ((threadIdx.x & 63) == 0) atomicMax(b2max, __float_as_int(mm));
}

// ---------------- Kernel 2: in-LDS fragment build + MFMA filter + exact rescore ----------------
// fp16-split distance matmul, K-slot pairing (sum_k A[i,k]*B[k,j] ~= |a|^2+|b|^2-2a.b):
//   k0-2 : a_hi      * -2*b_hi
//   k3-5 : a_lo      * -2*b_hi
//   k6-8 : a_hi      * -2*b_lo
//   k9,10: |a|^2 hi,lo * 1
//   k11,12: 1 * |b|^2 hi,lo
//   k13-31: 0
__global__ __launch_bounds__(256) void edge_kernel(
    const float4* __restrict__ dense,
    const int*    __restrict__ edge_index,
    const float*  __restrict__ b2max,
    float*        __restrict__ out)
{
    #pragma clang fp contract(off)   // exact path must match reference rounding

    const int e = blockIdx.x;
    const int t = threadIdx.x;

    __shared__ float4 x1s[P];                 // 2 KB
    __shared__ float4 x2s[P];                 // 2 KB
    __shared__ _Float16 sA[P * KROW];         // 10240 B
    __shared__ _Float16 sB[P * KROW];         // 10240 B
    __shared__ float wfmin[4];
    __shared__ unsigned long long wmin[4];

    const int c1 = edge_index[e];
    const int c2 = edge_index[NE + e];

    // Coalesced 4 KB stage of both clusters' coords from the L2-resident dense array.
    if (t < P) x1s[t]     = dense[c1 * P + t];
    else       x2s[t - P] = dense[c2 * P + (t - P)];
    __syncthreads();

    // In-LDS fragment build: thread t<128 builds A-row for x1 point t,
    // t>=128 builds B-row for x2 point t-128. Slots 13..31 zeroed (read by
    // MFMA quads 2,3); pad 32..39 never read.
    {
        const bool isA = (t < P);
        const int  p   = isA ? t : (t - P);
        const float4 c = isA ? x1s[p] : x2s[p];
        const float x = c.x, y = c.y, z = c.z;

        const _Float16 xh = (_Float16)x, yh = (_Float16)y, zh = (_Float16)z;
        const _Float16 xl = (_Float16)(x - (float)xh);
        const _Float16 yl = (_Float16)(y - (float)yh);
        const _Float16 zl = (_Float16)(z - (float)zh);
        const float s2 = x * x + y * y + z * z;
        const _Float16 s2h = (_Float16)s2;
        const _Float16 s2l = (_Float16)(s2 - (float)s2h);
        const _Float16 one = (_Float16)1.0f;
        const _Float16 n2  = (_Float16)(-2.0f);

        _Float16 row[32];
        #pragma unroll
        for (int k = 13; k < 32; ++k) row[k] = (_Float16)0.f;
        if (isA) {
            row[0] = xh;  row[1] = yh;  row[2] = zh;
            row[3] = xl;  row[4] = yl;  row[5] = zl;
            row[6] = xh;  row[7] = yh;  row[8] = zh;
            row[9] = s2h; row[10] = s2l; row[11] = one; row[12] = one;
        } else {
            const _Float16 m2xh = n2 * xh, m2yh = n2 * yh, m2zh = n2 * zh; // exact (x2)
            const _Float16 m2xl = n2 * xl, m2yl = n2 * yl, m2zl = n2 * zl;
            row[0] = m2xh; row[1] = m2yh; row[2] = m2zh;
            row[3] = m2xh; row[4] = m2yh; row[5] = m2zh;
            row[6] = m2xl; row[7] = m2yl; row[8] = m2zl;
            row[9] = one;  row[10] = one; row[11] = s2h; row[12] = s2l;
        }
        ulonglong2* dst = (ulonglong2*)&(isA ? sA : sB)[p * KROW];  // 80B rows, 16B-aligned
        const ulonglong2* src = (const ulonglong2*)row;
        #pragma unroll
        for (int k = 0; k < 4; ++k) dst[k] = src[k];
    }
    __syncthreads();

    const int lane = t & 63, w = t >> 6;
    const int m = lane & 15, quad = lane >> 4;

    // A frags: wave w owns rows [32w, 32w+32) as two 16-row tiles.
    const half8 a0 = *(const half8*)&sA[(w * 32 +      m) * KROW + quad * 8];
    const half8 a1 = *(const half8*)&sA[(w * 32 + 16 + m) * KROW + quad * 8];

    float4v acc[2][8];
    #pragma unroll
    for (int tr = 0; tr < 2; ++tr)
        #pragma unroll
        for (int tc = 0; tc < 8; ++tc)
            acc[tr][tc] = (float4v){0.f, 0.f, 0.f, 0.f};

    #pragma unroll
    for (int tc = 0; tc < 8; ++tc) {
        const half8 b = *(const half8*)&sB[(tc * 16 + m) * KROW + quad * 8];
        acc[0][tc] = __builtin_amdgcn_mfma_f32_16x16x32_f16(a0, b, acc[0][tc], 0, 0, 0);
        acc[1][tc] = __builtin_amdgcn_mfma_f32_16x16x32_f16(a1, b, acc[1][tc], 0, 0, 0);
    }

    // Per-tile and per-lane min of the approximate distances.
    float tmin[16];
    #pragma unroll
    for (int tr = 0; tr < 2; ++tr)
        #pragma unroll
        for (int tc = 0; tc < 8; ++tc) {
            const float4v vv = acc[tr][tc];
            tmin[tr * 8 + tc] = fminf(fminf(vv.x, vv.y), fminf(vv.z, vv.w));
        }
    float mymin = tmin[0];
    #pragma unroll
    for (int k = 1; k < 16; ++k) mymin = fminf(mymin, tmin[k]);

    for (int off = 32; off > 0; off >>= 1)
        mymin = fminf(mymin, __shfl_down(mymin, off, 64));
    if (lane == 0) wfmin[w] = mymin;
    __syncthreads();
    const float smin = fminf(fminf(wfmin[0], wfmin[1]), fminf(wfmin[2], wfmin[3]));

    // Rigorous filter margin: fp16-split error <= ~1.5e-4*B2 + denorm-flush slack.
    const float B2 = *b2max;
    const float tau = smin + (1.5e-4f * B2 + 8.0e-3f);

    // Exact rescoring of candidates only (reference fp32 rounding + tie-break).
    unsigned long long bestkey = ~0ull;
    #pragma unroll
    for (int tr = 0; tr < 2; ++tr) {
        #pragma unroll
        for (int tc = 0; tc < 8; ++tc) {
            if (tmin[tr * 8 + tc] <= tau) {
                const float4v vv = acc[tr][tc];
                #pragma unroll
                for (int r = 0; r < 4; ++r) {
                    const float sv = (r == 0) ? vv.x : (r == 1) ? vv.y : (r == 2) ? vv.z : vv.w;
                    if (sv <= tau) {
                        // C/D layout: col = lane&15, row = quad*4 + r
                        const int i = w * 32 + tr * 16 + quad * 4 + r;
                        const int j = tc * 16 + m;
                        const float4 pa = x1s[i];
                        const float4 pb = x2s[j];
                        const float dx = __fsub_rn(pa.x, pb.x);
                        const float dy = __fsub_rn(pa.y, pb.y);
                        const float dz = __fsub_rn(pa.z, pb.z);
                        const float d2 = __fadd_rn(__fadd_rn(__fmul_rn(dx, dx), __fmul_rn(dy, dy)),
                                                   __fmul_rn(dz, dz));
                        const unsigned long long key =
                            ((unsigned long long)__float_as_uint(d2) << 32) |
                            (unsigned)(i * P + j);
                        if (key < bestkey) bestkey = key;
                    }
                }
            }
        }
    }

    for (int off = 32; off > 0; off >>= 1) {
        unsigned long long other = __shfl_down(bestkey, off, 64);
        if (other < bestkey) bestkey = other;
    }
    if (lane == 0) wmin[w] = bestkey;
    __syncthreads();

    if (t == 0) {
        unsigned long long k0 = wmin[0];
        #pragma unroll
        for (int q = 1; q < 4; ++q) if (wmin[q] < k0) k0 = wmin[q];
        const int flat = (int)(k0 & 0xffffffffull);
        const int i1 = flat >> 7;
        const int i2 = flat & (P - 1);

        const float v1x = x1s[i1].x, v1y = x1s[i1].y, v1z = x1s[i1].z;
        const float v2x = x2s[i2].x, v2y = x2s[i2].y, v2z = x2s[i2].z;

        const float dx = v1x - v2x, dy = v1y - v2y, dz = v1z - v2z;
        const float lend = sqrtf(dx * dx + dy * dy + dz * dz);

        float nx, ny, nz;
        if (lend > 0.f) { nx = dx / lend; ny = dy / lend; nz = dz / lend; }
        else            { nx = dx;        ny = dy;        nz = dz;        }

        const float B[9] = { nx*nx, nx*ny, nx*nz,
                             ny*nx, ny*ny, ny*nz,
                             nz*nx, nz*ny, nz*nz };

        float* o = out + (size_t)e * 38;
        o[0] = v1x; o[1] = v1y; o[2] = v1z;
        o[3] = v2x; o[4] = v2y; o[5] = v2z;
        o[6] = nx;  o[7] = ny;  o[8] = nz;  o[9] = lend;
        #pragma unroll
        for (int q = 0; q < 9; ++q) o[10 + q] = B[q];
        o[19] = v2x; o[20] = v2y; o[21] = v2z;
        o[22] = v1x; o[23] = v1y; o[24] = v1z;
        o[25] = -nx; o[26] = -ny; o[27] = -nz; o[28] = lend;
        #pragma unroll
        for (int q = 0; q < 9; ++q) o[29 + q] = B[q];
    }
}

// ---------------- Fallback (ws too small): exact VALU kernel ----------------
__global__ __launch_bounds__(256) void exact_kernel(
    const float* __restrict__ data,
    const int*   __restrict__ clusts,
    const int*   __restrict__ edge_index,
    float*       __restrict__ out)
{
    #pragma clang fp contract(off)
    const int e = blockIdx.x;
    const int t = threadIdx.x;
    __shared__ float4 x1s[P];
    __shared__ float4 x2s[P];
    __shared__ unsigned long long wmin[4];
    const int c1 = edge_index[e];
    const int c2 = edge_index[NE + e];
    if (t < P) {
        const int v = clusts[c1 * P + t];
        x1s[t] = make_float4(data[v*NCOLS+1], data[v*NCOLS+2], data[v*NCOLS+3], 0.f);
    } else {
        const int p = t - P;
        const int v = clusts[c2 * P + p];
        x2s[p] = make_float4(data[v*NCOLS+1], data[v*NCOLS+2], data[v*NCOLS+3], 0.f);
    }
    __syncthreads();
    const int tj = t & 15, ti = t >> 4;
    float4 a[8], b[8];
    #pragma unroll
    for (int k = 0; k < 8; ++k) a[k] = x1s[ti + 16*k];
    #pragma unroll
    for (int mm = 0; mm < 8; ++mm) b[mm] = x2s[tj + 16*mm];
    float bd[8]; int bj[8];
    #pragma unroll
    for (int k = 0; k < 8; ++k) { bd[k] = __builtin_inff(); bj[k] = 0; }
    #pragma unroll
    for (int mm = 0; mm < 8; ++mm) {
        const int j = tj + 16*mm;
        #pragma unroll
        for (int k = 0; k < 8; ++k) {
            const float dx = __fsub_rn(a[k].x, b[mm].x);
            const float dy = __fsub_rn(a[k].y, b[mm].y);
            const float dz = __fsub_rn(a[k].z, b[mm].z);
            const float d2 = __fadd_rn(__fadd_rn(__fmul_rn(dx,dx), __fmul_rn(dy,dy)), __fmul_rn(dz,dz));
            if (d2 < bd[k]) { bd[k] = d2; bj[k] = j; }
        }
    }
    float bestd = __builtin_inff(); int bestflat = 0;
    #pragma unroll
    for (int k = 0; k < 8; ++k)
        if (bd[k] < bestd) { bestd = bd[k]; bestflat = (ti + 16*k) * P + bj[k]; }
    unsigned long long key = ((unsigned long long)__float_as_uint(bestd) << 32) | (unsigned)bestflat;
    for (int off = 32; off > 0; off >>= 1) {
        unsigned long long other = __shfl_down(key, off, 64);
        if (other < key) key = other;
    }
    if ((t & 63) == 0) wmin[t >> 6] = key;
    __syncthreads();
    if (t == 0) {
        unsigned long long k0 = wmin[0];
        #pragma unroll
        for (int q = 1; q < 4; ++q) if (wmin[q] < k0) k0 = wmin[q];
        const int flat = (int)(k0 & 0xffffffffull);
        const int i1 = flat >> 7, i2 = flat & (P - 1);
        const float v1x = x1s[i1].x, v1y = x1s[i1].y, v1z = x1s[i1].z;
        const float v2x = x2s[i2].x, v2y = x2s[i2].y, v2z = x2s[i2].z;
        const float dx = v1x - v2x, dy = v1y - v2y, dz = v1z - v2z;
        const float lend = sqrtf(dx*dx + dy*dy + dz*dz);
        float nx, ny, nz;
        if (lend > 0.f) { nx = dx/lend; ny = dy/lend; nz = dz/lend; }
        else            { nx = dx; ny = dy; nz = dz; }
        const float B[9] = { nx*nx, nx*ny, nx*nz, ny*nx, ny*ny, ny*nz, nz*nx, nz*ny, nz*nz };
        float* o = out + (size_t)e * 38;
        o[0]=v1x; o[1]=v1y; o[2]=v1z; o[3]=v2x; o[4]=v2y; o[5]=v2z;
        o[6]=nx; o[7]=ny; o[8]=nz; o[9]=lend;
        #pragma unroll
        for (int q = 0; q < 9; ++q) o[10+q] = B[q];
        o[19]=v2x; o[20]=v2y; o[21]=v2z; o[22]=v1x; o[23]=v1y; o[24]=v1z;
        o[25]=-nx; o[26]=-ny; o[27]=-nz; o[28]=lend;
        #pragma unroll
        for (int q = 0; q < 9; ++q) o[29+q] = B[q];
    }
}

extern "C" void kernel_launch(void* const* d_in, const int* in_sizes, int n_in,
                              void* d_out, int out_size, void* d_ws, size_t ws_size,
                              hipStream_t stream) {
    const float* data       = (const float*)d_in[0];
    const int*   clusts     = (const int*)d_in[1];
    const int*   edge_index = (const int*)d_in[2];
    float*       out        = (float*)d_out;

    char* wsc = (char*)d_ws;
    const size_t denseOff = 256;
    const size_t denseBytes = (size_t)NC * P * sizeof(float4);   // 2 MB
    const size_t need = denseOff + denseBytes;

    if (ws_size >= need) {
        int*    b2max = (int*)wsc;
        float4* dense = (float4*)(wsc + denseOff);
        gather_kernel<<<(NC * P) / 256, 256, 0, stream>>>(data, clusts, dense, b2max);
        edge_kernel<<<NE, 256, 0, stream>>>(dense, edge_index, (const float*)b2max, out);
    } else {
        exact_kernel<<<NE, 256, 0, stream>>>(data, clusts, edge_index, out);
    }
}